// Round 1
// baseline (675.706 us; speedup 1.0000x reference)
//
#include <hip/hip_runtime.h>

// Chunked VMM with per-128-K-chunk ADC quantization.
//   out[b,n] = sum_{c} q( sum_{k in chunk c} x[b,k]*w[n,k] ) + bias[n]
//   q(p) = round(clip(p,+-2.56) * 255/2.56) * 2.56/255   (round = RTNE)
// w pre-scaled by s=255/2.56 so GEMM partials are in ADC units.
//
// R4: counted-vmcnt phase pipeline (T3+T4 port).
//   Tile 128x256, BK=64, 8 waves of 64x64 (4x4 mfma_16x16x32_bf16 frags).
//   LDS 96 KiB double-buffered, stored as K-chunk planes (2 chunks of 32
//   K-cols per tile) so staging order == consumption order. Each phase:
//   fused "s_waitcnt vmcnt(3); s_barrier" (NEVER drain to 0), 8 ds_read_b128,
//   stage next tile's matching chunk (3 global_load_lds w16), setprio(1),
//   16 MFMA, setprio(0). Chunk staged 2 phases (~1200cy) before its read.
//   XOR swizzle c^=(r&3)^((r>>2)&3) on 16B cols via pre-swizzled global src
//   + swizzled ds_read (involution both sides) -> conflict-free b128 beats.
//   Quantize every loop iter (=128 K), register-only, sinks under next MFMA.

typedef __attribute__((ext_vector_type(8))) short short8;            // 8 bf16
typedef __attribute__((ext_vector_type(8))) unsigned short ushort8;  // 16 B store
typedef __attribute__((ext_vector_type(4))) float floatx4;           // MFMA C/D

#define BM 128
#define BN 256
#define BK 64

static __device__ __forceinline__ unsigned short f2bf(float f) {
    union { float f; unsigned int u; } v; v.f = f;
    unsigned int u = v.u;
    unsigned int r = (u + 0x7fffu + ((u >> 16) & 1u)) >> 16;  // RTNE
    return (unsigned short)r;
}

// fp32 -> bf16 with scale; 8 elements/lane/iter: 32B read, 16B write.
__global__ void cast_kernel(const float* __restrict__ in,
                            unsigned short* __restrict__ out,
                            long n8, float s) {
    long i = (long)blockIdx.x * 256 + threadIdx.x;
    const long stride = (long)gridDim.x * 256;
    for (; i < n8; i += stride) {
        float4 a = ((const float4*)in)[2 * i];
        float4 b = ((const float4*)in)[2 * i + 1];
        ushort8 o;
        o[0] = f2bf(a.x * s); o[1] = f2bf(a.y * s);
        o[2] = f2bf(a.z * s); o[3] = f2bf(a.w * s);
        o[4] = f2bf(b.x * s); o[5] = f2bf(b.y * s);
        o[6] = f2bf(b.z * s); o[7] = f2bf(b.w * s);
        ((ushort8*)out)[i] = o;
    }
}

__global__ __launch_bounds__(512, 2) void vmm_kernel(
    const unsigned short* __restrict__ A,   // x   [B,K] bf16
    const unsigned short* __restrict__ Bw,  // w*s [N,K] bf16 (K-contiguous: B^T gemm)
    const float* __restrict__ bias,
    float* __restrict__ out,
    int N, int K)
{
    // K-chunk-plane layout, all offsets in shorts:
    //   sA[buf(8192)][chunk kk(4096)] : chunk = 128 rows x 32 cols
    //   sB[buf(16384)][chunk kk(8192)]: chunk = 256 rows x 32 cols
    __shared__ unsigned short sA[2 * BM * BK];   // 32 KiB
    __shared__ unsigned short sB[2 * BN * BK];   // 64 KiB

    const int tid  = threadIdx.x;
    const int wid  = tid >> 6;
    const int lane = tid & 63;

    const int m0 = blockIdx.y * BM;
    const int n0 = blockIdx.x * BN;

    const int waveM = (wid >> 2) * 64;   // 0,64
    const int waveN = (wid & 3) * 64;    // 0,64,128,192

    // ---- staging mapping: thread t -> physical (row=t>>2, 16Bcol=t&3) of a
    // chunk; fetches LOGICAL col (t&3)^f(row), f(r)=(r&3)^((r>>2)&3).
    const int scl = ((tid & 3) ^ ((tid >> 2) & 3) ^ ((tid >> 4) & 3)) * 8;
    const unsigned short* srcA  = A  + (long)(m0 + (tid >> 2)) * K + scl;
    const unsigned short* srcB0 = Bw + (long)(n0 + (tid >> 2)) * K + scl;
    const unsigned short* srcB1 = srcB0 + (long)128 * K;
    unsigned short* dA = sA + wid * 512;   // wave-uniform; HW adds lane*16B
    unsigned short* dB = sB + wid * 512;

    // ---- ds_read mapping: frag row = waveX + t*16 + (lane&15), physical
    // 16B col = (lane>>4) ^ f(row); f(row) reduces to lane-only bits.
    const int cpl = ((lane >> 4) ^ (lane & 3) ^ ((lane >> 2) & 3)) * 8;
    int aoff[4], boff[4];
    #pragma unroll
    for (int t = 0; t < 4; ++t) {
        aoff[t] = (waveM + t * 16 + (lane & 15)) * 32 + cpl;
        boff[t] = (waveN + t * 16 + (lane & 15)) * 32 + cpl;
    }

    floatx4 acc[4][4];   // partial (ADC units), quantized+reset every 128 K
    floatx4 macc[4][4];  // master accumulator
    #pragma unroll
    for (int i = 0; i < 4; ++i)
        #pragma unroll
        for (int j = 0; j < 4; ++j) {
            acc[i][j]  = (floatx4){0.f, 0.f, 0.f, 0.f};
            macc[i][j] = (floatx4){0.f, 0.f, 0.f, 0.f};
        }

    // stage chunk kk (K cols [sk+32kk, sk+32kk+32)) of next tile into buf sbuf:
    // exactly 3 vmem ops per thread, in fixed program order (vmcnt FIFO).
    #define STAGE(sbuf, kk, sk) do {                                            \
        __builtin_amdgcn_global_load_lds(                                       \
            (const __attribute__((address_space(1))) void*)(srcA + (sk) + (kk) * 32), \
            (__attribute__((address_space(3))) void*)(dA + (sbuf) * 8192 + (kk) * 4096), \
            16, 0, 0);                                                          \
        __builtin_amdgcn_global_load_lds(                                       \
            (const __attribute__((address_space(1))) void*)(srcB0 + (sk) + (kk) * 32), \
            (__attribute__((address_space(3))) void*)(dB + (sbuf) * 16384 + (kk) * 8192), \
            16, 0, 0);                                                          \
        __builtin_amdgcn_global_load_lds(                                       \
            (const __attribute__((address_space(1))) void*)(srcB1 + (sk) + (kk) * 32), \
            (__attribute__((address_space(3))) void*)(dB + (sbuf) * 16384 + (kk) * 8192 + 4096), \
            16, 0, 0);                                                          \
    } while (0)

    // One phase: wait ONLY for the chunk about to be read (3 oldest of 6 in
    // flight), barrier for cross-wave visibility, read frags, prefetch the
    // matching chunk of the next tile, 16 MFMAs.
    #define PHASE(rbuf, kk, sbuf, sk) do {                                      \
        asm volatile("s_waitcnt vmcnt(3)\n\ts_barrier" ::: "memory");           \
        const unsigned short* pa_ = sA + (rbuf) * 8192 + (kk) * 4096;           \
        const unsigned short* pb_ = sB + (rbuf) * 16384 + (kk) * 8192;          \
        short8 af_[4], bf_[4];                                                  \
        _Pragma("unroll")                                                       \
        for (int t = 0; t < 4; ++t) af_[t] = *(const short8*)(pa_ + aoff[t]);   \
        _Pragma("unroll")                                                       \
        for (int t = 0; t < 4; ++t) bf_[t] = *(const short8*)(pb_ + boff[t]);   \
        STAGE(sbuf, kk, sk);                                                    \
        __builtin_amdgcn_s_setprio(1);                                          \
        _Pragma("unroll")                                                       \
        for (int tm = 0; tm < 4; ++tm)                                          \
            _Pragma("unroll")                                                   \
            for (int tn = 0; tn < 4; ++tn)                                      \
                acc[tm][tn] = __builtin_amdgcn_mfma_f32_16x16x32_bf16(          \
                    af_[tm], bf_[tn], acc[tm][tn], 0, 0, 0);                    \
        __builtin_amdgcn_s_setprio(0);                                          \
    } while (0)

    // prologue: stage tile 0 into buf0 (chunk order 0 then 1 -> FIFO matches)
    STAGE(0, 0, 0);
    STAGE(0, 1, 0);

    for (int k0 = 0; k0 < K; k0 += 128) {
        const int skA = k0 + 64;                          // tile t+1 source
        const int skB = (k0 + 128 < K) ? (k0 + 128) : 0;  // tile t+2 (wrap: harmless)
        PHASE(0, 0, 1, skA);   // compute tile t   (buf0), stage tile t+1 -> buf1
        PHASE(0, 1, 1, skA);
        PHASE(1, 0, 0, skB);   // compute tile t+1 (buf1), stage tile t+2 -> buf0
        PHASE(1, 1, 0, skB);

        // ADC quantize at the 128-K boundary; register-only, scheduler may
        // sink it under the next tile's MFMA phases (deps keep it correct).
        #pragma unroll
        for (int tm = 0; tm < 4; ++tm)
            #pragma unroll
            for (int tn = 0; tn < 4; ++tn) {
                #pragma unroll
                for (int r = 0; r < 4; ++r) {
                    float v = acc[tm][tn][r];
                    v = __builtin_amdgcn_fmed3f(v, -255.0f, 255.0f); // clamp
                    v = __builtin_rintf(v);                          // v_rndne
                    macc[tm][tn][r] += v;
                }
                acc[tm][tn] = (floatx4){0.f, 0.f, 0.f, 0.f};
            }
    }
    asm volatile("s_waitcnt vmcnt(0)" ::: "memory");  // drain trailing stages

    const float invs = 2.56f / 255.0f;
    #pragma unroll
    for (int tn = 0; tn < 4; ++tn) {
        const int col = n0 + waveN + tn * 16 + (lane & 15);
        const float bv = bias[col];
        #pragma unroll
        for (int tm = 0; tm < 4; ++tm) {
            const int row = m0 + waveM + tm * 16 + (lane >> 4) * 4;
            #pragma unroll
            for (int r = 0; r < 4; ++r)
                out[(long)(row + r) * N + col] = macc[tm][tn][r] * invs + bv;
        }
    }
    #undef PHASE
    #undef STAGE
}

extern "C" void kernel_launch(void* const* d_in, const int* in_sizes, int n_in,
                              void* d_out, int out_size, void* d_ws, size_t ws_size,
                              hipStream_t stream) {
    const float* x    = (const float*)d_in[0];
    const float* w    = (const float*)d_in[1];
    const float* bias = (const float*)d_in[2];
    // d_in[3] = layer (unused)

    const int N = in_sizes[2];
    const int K = in_sizes[1] / N;
    const int B = in_sizes[0] / K;
    float* out = (float*)d_out;

    // workspace layout: bf16 x [B*K], bf16 w*s [N*K]  (needs ~101 MB)
    unsigned short* xb = (unsigned short*)d_ws;
    unsigned short* wb = xb + (size_t)B * K;

    cast_kernel<<<2048, 256, 0, stream>>>(x, xb, ((long)B * K) / 8, 1.0f);
    cast_kernel<<<2048, 256, 0, stream>>>(w, wb, ((long)N * K) / 8, 99.609375f);

    dim3 grid(N / BN, B / BM);   // (16, 64)
    vmm_kernel<<<grid, 512, 0, stream>>>(xb, wb, bias, out, N, K);
}

// Round 2
// 593.206 us; speedup vs baseline: 1.1391x; 1.1391x over previous
//
#include <hip/hip_runtime.h>

// Chunked VMM with per-128-K-chunk ADC quantization.
//   out[b,n] = sum_{c} q( sum_{k in chunk c} x[b,k]*w[n,k] ) + bias[n]
//   q(p) = round(clip(p,+-2.56) * 255/2.56) * 2.56/255   (round = RTNE)
// w pre-scaled by s=255/2.56 so GEMM partials are in ADC units.
//
// R5: XCD-local staging + proven LDS layout + tile-deep counted-vmcnt.
//  - Supertile XCD map: xcd g owns m-tiles [8g,8g+8); concurrent 32 blocks
//    per XCD = 8m x 4n supertile -> staging K-window (256KB) lives in the
//    XCD's 4MB L2 instead of thrashing to L3 (R4: ~7 TB/s L3 demand).
//  - LDS: row-major [rows][BK=64] tiles, chunk swizzle pc = lc ^ (row&7)
//    (R3-measured 0 bank conflicts; R4's chunk-plane swizzle measured
//    4 extra cyc per ds_read_b128). Triple-buffered: 3 x (16+32)KB = 144KB.
//  - Pipeline: one barrier per BK-tile; stage tile t+2 during tile t
//    (6 global_load_lds w16 per tile); constant s_waitcnt vmcnt(6) per
//    tile (never 0 in main loop), peeled tail vmcnt(6)/vmcnt(0).
//  - Tile 128x256, 8 waves of 64x64 (4x4 mfma_16x16x32_bf16), quantize
//    (fmed3 clamp, v_rndne, macc add) after every odd tile (=128 K).

typedef __attribute__((ext_vector_type(8))) short short8;            // 8 bf16
typedef __attribute__((ext_vector_type(8))) unsigned short ushort8;  // 16 B store
typedef __attribute__((ext_vector_type(4))) float floatx4;           // MFMA C/D

#define BM 128
#define BN 256
#define BK 64

#define AS1 __attribute__((address_space(1)))
#define AS3 __attribute__((address_space(3)))

static __device__ __forceinline__ unsigned short f2bf(float f) {
    union { float f; unsigned int u; } v; v.f = f;
    unsigned int u = v.u;
    unsigned int r = (u + 0x7fffu + ((u >> 16) & 1u)) >> 16;  // RTNE
    return (unsigned short)r;
}

// fp32 -> bf16 with scale; 8 elements/lane/iter: 32B read, 16B write.
__global__ void cast_kernel(const float* __restrict__ in,
                            unsigned short* __restrict__ out,
                            long n8, float s) {
    long i = (long)blockIdx.x * 256 + threadIdx.x;
    const long stride = (long)gridDim.x * 256;
    for (; i < n8; i += stride) {
        float4 a = ((const float4*)in)[2 * i];
        float4 b = ((const float4*)in)[2 * i + 1];
        ushort8 o;
        o[0] = f2bf(a.x * s); o[1] = f2bf(a.y * s);
        o[2] = f2bf(a.z * s); o[3] = f2bf(a.w * s);
        o[4] = f2bf(b.x * s); o[5] = f2bf(b.y * s);
        o[6] = f2bf(b.z * s); o[7] = f2bf(b.w * s);
        ((ushort8*)out)[i] = o;
    }
}

__global__ __launch_bounds__(512, 2) void vmm_kernel(
    const unsigned short* __restrict__ A,   // x   [B,K] bf16
    const unsigned short* __restrict__ Bw,  // w*s [N,K] bf16 (K-contiguous: B^T gemm)
    const float* __restrict__ bias,
    float* __restrict__ out,
    int N, int K)
{
    // Triple-buffered row-major tiles (shorts): sA[3][128][64], sB[3][256][64]
    __shared__ unsigned short sA[3 * BM * BK];   // 48 KiB
    __shared__ unsigned short sB[3 * BN * BK];   // 96 KiB

    const int tid  = threadIdx.x;
    const int wid  = tid >> 6;
    const int lane = tid & 63;

    // ---- XCD supertile block mapping (grid is 1-D, 1024 blocks) -----------
    // xcd = bid&7 (round-robin dispatch heuristic). XCD g owns m-tiles
    // [8g, 8g+8); within it, idx = bid>>3 decodes round r (n-group) + slot.
    const int ntn = N / BN;                      // 16
    int mt, ntile;
    if (gridDim.x == 1024 && ntn == 16) {
        const int g   = blockIdx.x & 7;
        const int idx = blockIdx.x >> 3;         // 0..127
        mt    = (g << 3) + ((idx >> 2) & 7);     // 0..63
        ntile = ((idx >> 5) << 2) + (idx & 3);   // 0..15
    } else {                                     // generic fallback
        mt = blockIdx.x / ntn;
        ntile = blockIdx.x - mt * ntn;
    }
    const int m0 = mt * BM;
    const int n0 = ntile * BN;

    const int waveM = (wid >> 2) * 64;   // 0,64
    const int waveN = (wid & 3) * 64;    // 0,64,128,192

    // ---- staging: each wave-load covers one 1KiB segment = 8 rows x 64 cols.
    // lane -> (row-in-seg = lane>>3, physical chunk = lane&7); fetch global
    // logical chunk (lane&7) ^ (row&7) so that pc = lc ^ (row&7).
    const int r0  = (wid << 3) + (lane >> 3);              // row base in 64-row group
    const int csw = (((lane & 7) ^ (lane >> 3)) << 3);     // swizzled col (shorts)
    const unsigned short* gA = A  + (long)(m0 + r0) * K + csw;
    const unsigned short* gB = Bw + (long)(n0 + r0) * K + csw;

    // ---- ds_read mapping: frag row = waveX + tm*16 + (lane&15); logical
    // chunk = (kk>>3) + (lane>>4); pc = lc ^ (row&7), row&7 == lane&7.
    const int c0 = (((lane >> 4) ^ (lane & 7)) << 3);      // kk=0 chunk offset
    int aoff[4], boff[4];
    #pragma unroll
    for (int t = 0; t < 4; ++t) {
        aoff[t] = (waveM + t * 16 + (lane & 15)) * BK + c0;
        boff[t] = (waveN + t * 16 + (lane & 15)) * BK + c0;
    }
    // kk=32 half: offset ^ 32 (flips chunk bit2: (4^u)^v == (u^v)^4)

    floatx4 acc[4][4];   // partial (ADC units), quantized+reset every 128 K
    floatx4 macc[4][4];  // master accumulator
    #pragma unroll
    for (int i = 0; i < 4; ++i)
        #pragma unroll
        for (int j = 0; j < 4; ++j) {
            acc[i][j]  = (floatx4){0.f, 0.f, 0.f, 0.f};
            macc[i][j] = (floatx4){0.f, 0.f, 0.f, 0.f};
        }

    // 6 loads per tile, fixed program order (vmcnt FIFO): A segs {w, 8+w},
    // B segs {w, 8+w, 16+w, 24+w}; seg s -> LDS offset s*512 shorts.
    #define STAGE(buf, ksrc) do {                                              \
        const long ko_ = (ksrc);                                               \
        __builtin_amdgcn_global_load_lds((const AS1 void*)(gA + ko_),          \
            (AS3 void*)(sA + (buf) * 8192 + wid * 512), 16, 0, 0);             \
        __builtin_amdgcn_global_load_lds((const AS1 void*)(gA + 64 * (long)K + ko_), \
            (AS3 void*)(sA + (buf) * 8192 + 4096 + wid * 512), 16, 0, 0);      \
        __builtin_amdgcn_global_load_lds((const AS1 void*)(gB + ko_),          \
            (AS3 void*)(sB + (buf) * 16384 + wid * 512), 16, 0, 0);            \
        __builtin_amdgcn_global_load_lds((const AS1 void*)(gB + 64 * (long)K + ko_), \
            (AS3 void*)(sB + (buf) * 16384 + 4096 + wid * 512), 16, 0, 0);     \
        __builtin_amdgcn_global_load_lds((const AS1 void*)(gB + 128 * (long)K + ko_), \
            (AS3 void*)(sB + (buf) * 16384 + 8192 + wid * 512), 16, 0, 0);     \
        __builtin_amdgcn_global_load_lds((const AS1 void*)(gB + 192 * (long)K + ko_), \
            (AS3 void*)(sB + (buf) * 16384 + 12288 + wid * 512), 16, 0, 0);    \
    } while (0)

    const int NT = K / BK;   // 64 tiles
    STAGE(0, 0);             // t0
    STAGE(1, BK);            // t1  -> 12 loads outstanding

    int buf = 0;
    for (int t = 0; t < NT; ++t) {
        // Wait for tile t's 6 loads (oldest); keep tile t+1's 6 in flight.
        // Tail: at t==NT-1 only 6 remain -> must drain fully.
        if (t < NT - 1)
            asm volatile("s_waitcnt vmcnt(6)\n\ts_barrier" ::: "memory");
        else
            asm volatile("s_waitcnt vmcnt(0)\n\ts_barrier" ::: "memory");
        // Barrier also proves all waves finished reading tile t-1 -> safe to
        // overwrite buf[(t+2)%3] (holds t-1) with tile t+2's DMA below.

        const unsigned short* pa = sA + buf * 8192;
        const unsigned short* pb = sB + buf * 16384;
        short8 af[2][4], bfr[2][4];
        #pragma unroll
        for (int tm = 0; tm < 4; ++tm) {
            af[0][tm] = *(const short8*)(pa + aoff[tm]);
            af[1][tm] = *(const short8*)(pa + (aoff[tm] ^ 32));
        }
        #pragma unroll
        for (int tn = 0; tn < 4; ++tn) {
            bfr[0][tn] = *(const short8*)(pb + boff[tn]);
            bfr[1][tn] = *(const short8*)(pb + (boff[tn] ^ 32));
        }

        if (t + 2 < NT) {
            const int nb = (buf >= 1) ? buf - 1 : 2;   // (t+2)%3
            STAGE(nb, (long)(t + 2) * BK);
        }

        __builtin_amdgcn_s_setprio(1);
        #pragma unroll
        for (int h = 0; h < 2; ++h)
            #pragma unroll
            for (int tm = 0; tm < 4; ++tm)
                #pragma unroll
                for (int tn = 0; tn < 4; ++tn)
                    acc[tm][tn] = __builtin_amdgcn_mfma_f32_16x16x32_bf16(
                        af[h][tm], bfr[h][tn], acc[tm][tn], 0, 0, 0);
        __builtin_amdgcn_s_setprio(0);

        // ADC quantize at each 128-K boundary (after every odd tile).
        if (t & 1) {
            #pragma unroll
            for (int tm = 0; tm < 4; ++tm)
                #pragma unroll
                for (int tn = 0; tn < 4; ++tn) {
                    #pragma unroll
                    for (int r = 0; r < 4; ++r) {
                        float v = acc[tm][tn][r];
                        v = __builtin_amdgcn_fmed3f(v, -255.0f, 255.0f); // clamp
                        v = __builtin_rintf(v);                          // v_rndne
                        macc[tm][tn][r] += v;
                    }
                    acc[tm][tn] = (floatx4){0.f, 0.f, 0.f, 0.f};
                }
        }
        buf = (buf == 2) ? 0 : buf + 1;
    }

    const float invs = 2.56f / 255.0f;
    #pragma unroll
    for (int tn = 0; tn < 4; ++tn) {
        const int col = n0 + waveN + tn * 16 + (lane & 15);
        const float bv = bias[col];
        #pragma unroll
        for (int tm = 0; tm < 4; ++tm) {
            const int row = m0 + waveM + tm * 16 + (lane >> 4) * 4;
            #pragma unroll
            for (int r = 0; r < 4; ++r)
                out[(long)(row + r) * N + col] = macc[tm][tn][r] * invs + bv;
        }
    }
    #undef STAGE
}

extern "C" void kernel_launch(void* const* d_in, const int* in_sizes, int n_in,
                              void* d_out, int out_size, void* d_ws, size_t ws_size,
                              hipStream_t stream) {
    const float* x    = (const float*)d_in[0];
    const float* w    = (const float*)d_in[1];
    const float* bias = (const float*)d_in[2];
    // d_in[3] = layer (unused)

    const int N = in_sizes[2];
    const int K = in_sizes[1] / N;
    const int B = in_sizes[0] / K;
    float* out = (float*)d_out;

    // workspace layout: bf16 x [B*K], bf16 w*s [N*K]  (needs ~101 MB)
    unsigned short* xb = (unsigned short*)d_ws;
    unsigned short* wb = xb + (size_t)B * K;

    cast_kernel<<<2048, 256, 0, stream>>>(x, xb, ((long)B * K) / 8, 1.0f);
    cast_kernel<<<2048, 256, 0, stream>>>(w, wb, ((long)N * K) / 8, 99.609375f);

    const int nblocks = (N / BN) * (B / BM);   // 16 * 64 = 1024
    vmm_kernel<<<nblocks, 512, 0, stream>>>(xb, wb, bias, out, N, K);
}